// Round 15
// baseline (1861.217 us; speedup 1.0000x reference)
//
#include <hip/hip_runtime.h>
#include <float.h>

// ---------------------------------------------------------------------------
// VQ-VAE quantizer forward — round 15: round-14 pipeline (PASSED, 1486 us):
//  * screen: K-stage 64 (half the barriers), wave-shuffle min before atomicMin
//    (16x fewer LDS atomics -> epilogue conflicts gone).
//  * zsplit fused into the z emul_gemm epilogue (packed bf16x2 out of regs);
//    zpack lives in the o_zq region, recs in the dead t region.
//  * gather_zq + embedding sqdiff folded into collect_rescore.
// ids semantics unchanged: certified bf16x2 MFMA screen (DELTA=1.2e-3) +
// exact sequential-k chain rescore (panel joins k=384,704) = np first-index.
// ---------------------------------------------------------------------------

#define N_ROWS 8192
#define IN_DIM 2048
#define DIM 1024
#define CBK 8192

#define PANEL_MASK_K1024_C32 0x0000000000401000ULL  // joins k=384,704
#define PANEL_MASK_K2048_C32 0x0101001001001000ULL  // k=384,768,1152,1536,1792

#define SCREEN_DELTA 1.2e-3f

typedef __attribute__((ext_vector_type(8))) short short8;
typedef __attribute__((ext_vector_type(8))) unsigned short ushort8;
typedef __attribute__((ext_vector_type(4))) float f32x4;

__device__ __forceinline__ float sqf(float v) { return __builtin_fmaf(v, v, 0.0f); }

__device__ __forceinline__ unsigned short f2bf(float f) {  // RNE f32->bf16
  unsigned int u = __float_as_uint(f);
  u += 0x7fffu + ((u >> 16) & 1u);
  return (unsigned short)(u >> 16);
}

// truncation split x = hi + rem; pack (hi>>16) | (trunc_bf16(rem) bits)
__device__ __forceinline__ unsigned packsplit(float x) {
  const unsigned u = __float_as_uint(x);
  const unsigned hb = u & 0xFFFF0000u;
  const float rem = x - __uint_as_float(hb);
  return (u >> 16) | (__float_as_uint(rem) & 0xFFFF0000u);
}

__device__ __forceinline__ int swz128(int c) {
  return (c & 3) | (((c >> 3) & 7) << 2) | (((c >> 2) & 1) << 5) | ((c >> 6) << 6);
}

__device__ __forceinline__ float block_reduce_sum(float v) {
  __shared__ float sh[4];
  #pragma unroll
  for (int off = 32; off > 0; off >>= 1) v += __shfl_down(v, off, 64);
  const int lane = threadIdx.x & 63, w = threadIdx.x >> 6;
  if (lane == 0) sh[w] = v;
  __syncthreads();
  float r = 0.f;
  if (threadIdx.x == 0) r = sh[0] + sh[1] + sh[2] + sh[3];
  return r;  // valid on thread 0 only
}

// exact emulated-f32 distance: sequential-k chain, panel joins at 384/704.
__device__ __forceinline__ float chain_d(const float* __restrict__ zsh,
                                         const float* __restrict__ cbr,
                                         float z2r, float c2e) {
  float part = 0.f;
  for (int k = 0; k < 384; ++k) part = __builtin_fmaf(zsh[k], cbr[k], part);
  float total = part;
  part = 0.f;
  for (int k = 384; k < 704; ++k) part = __builtin_fmaf(zsh[k], cbr[k], part);
  total = total + part;
  part = 0.f;
  for (int k = 704; k < 1024; ++k) part = __builtin_fmaf(zsh[k], cbr[k], part);
  total = total + part;
  return __builtin_fmaf(-2.0f, total, z2r) + c2e;
}

// ---------------------------------------------------------------------------
// fp32 128x128x16 tiled GEMM (W_dc fusion only). Double-buffered. (r10 PASSED)
// ---------------------------------------------------------------------------
template <bool BT>
__global__ __launch_bounds__(256) void gemm128(
    const float* __restrict__ A, const float* __restrict__ B,
    const float* __restrict__ bias, float* __restrict__ C,
    int M, int N, int K) {
  __shared__ float As[2][16][132];
  __shared__ float Bs[2][16][132];
  const int tid = threadIdx.x;
  const int tx = tid & 15, ty = tid >> 4;
  const int bm = blockIdx.y, bn = blockIdx.x;

  const int mload = tid & 127, kh = tid >> 7;
  const size_t arow = (size_t)(bm * 128 + mload) * (size_t)K;
  const size_t brow = BT ? (size_t)(bn * 128 + mload) * (size_t)K : 0;
  const int swn = swz128(mload);
  const int c4 = (tid & 31) << 2;
  const int kr = tid >> 5;
  const int swc = swz128(c4);

  float acc[8][8];
  #pragma unroll
  for (int r = 0; r < 8; ++r)
    #pragma unroll
    for (int c = 0; c < 8; ++c) acc[r][c] = 0.f;

  const int boff = ((tx & 7) << 2) | ((tx >> 3) << 6);

  float4 av0, av1, bv0, bv1;
  av0 = *(const float4*)&A[arow + kh * 8];
  av1 = *(const float4*)&A[arow + kh * 8 + 4];
  if (BT) {
    bv0 = *(const float4*)&B[brow + kh * 8];
    bv1 = *(const float4*)&B[brow + kh * 8 + 4];
  } else {
    bv0 = *(const float4*)&B[(size_t)kr * N + bn * 128 + c4];
    bv1 = *(const float4*)&B[(size_t)(kr + 8) * N + bn * 128 + c4];
  }
  As[0][kh * 8 + 0][mload] = av0.x; As[0][kh * 8 + 1][mload] = av0.y;
  As[0][kh * 8 + 2][mload] = av0.z; As[0][kh * 8 + 3][mload] = av0.w;
  As[0][kh * 8 + 4][mload] = av1.x; As[0][kh * 8 + 5][mload] = av1.y;
  As[0][kh * 8 + 6][mload] = av1.z; As[0][kh * 8 + 7][mload] = av1.w;
  if (BT) {
    Bs[0][kh * 8 + 0][swn] = bv0.x; Bs[0][kh * 8 + 1][swn] = bv0.y;
    Bs[0][kh * 8 + 2][swn] = bv0.z; Bs[0][kh * 8 + 3][swn] = bv0.w;
    Bs[0][kh * 8 + 4][swn] = bv1.x; Bs[0][kh * 8 + 5][swn] = bv1.y;
    Bs[0][kh * 8 + 6][swn] = bv1.z; Bs[0][kh * 8 + 7][swn] = bv1.w;
  } else {
    *(float4*)&Bs[0][kr][swc] = bv0;
    *(float4*)&Bs[0][kr + 8][swc] = bv1;
  }
  const int nk = K >> 4;
  if (nk > 1) {
    av0 = *(const float4*)&A[arow + 16 + kh * 8];
    av1 = *(const float4*)&A[arow + 16 + kh * 8 + 4];
    if (BT) {
      bv0 = *(const float4*)&B[brow + 16 + kh * 8];
      bv1 = *(const float4*)&B[brow + 16 + kh * 8 + 4];
    } else {
      bv0 = *(const float4*)&B[(size_t)(16 + kr) * N + bn * 128 + c4];
      bv1 = *(const float4*)&B[(size_t)(16 + kr + 8) * N + bn * 128 + c4];
    }
  }
  __syncthreads();

  for (int ki = 0; ki < nk; ++ki) {
    const int p = ki & 1;
    if (ki + 1 < nk) {
      As[p ^ 1][kh * 8 + 0][mload] = av0.x; As[p ^ 1][kh * 8 + 1][mload] = av0.y;
      As[p ^ 1][kh * 8 + 2][mload] = av0.z; As[p ^ 1][kh * 8 + 3][mload] = av0.w;
      As[p ^ 1][kh * 8 + 4][mload] = av1.x; As[p ^ 1][kh * 8 + 5][mload] = av1.y;
      As[p ^ 1][kh * 8 + 6][mload] = av1.z; As[p ^ 1][kh * 8 + 7][mload] = av1.w;
      if (BT) {
        Bs[p ^ 1][kh * 8 + 0][swn] = bv0.x; Bs[p ^ 1][kh * 8 + 1][swn] = bv0.y;
        Bs[p ^ 1][kh * 8 + 2][swn] = bv0.z; Bs[p ^ 1][kh * 8 + 3][swn] = bv0.w;
        Bs[p ^ 1][kh * 8 + 4][swn] = bv1.x; Bs[p ^ 1][kh * 8 + 5][swn] = bv1.y;
        Bs[p ^ 1][kh * 8 + 6][swn] = bv1.z; Bs[p ^ 1][kh * 8 + 7][swn] = bv1.w;
      } else {
        *(float4*)&Bs[p ^ 1][kr][swc] = bv0;
        *(float4*)&Bs[p ^ 1][kr + 8][swc] = bv1;
      }
      if (ki + 2 < nk) {
        const int k2 = (ki + 2) << 4;
        av0 = *(const float4*)&A[arow + k2 + kh * 8];
        av1 = *(const float4*)&A[arow + k2 + kh * 8 + 4];
        if (BT) {
          bv0 = *(const float4*)&B[brow + k2 + kh * 8];
          bv1 = *(const float4*)&B[brow + k2 + kh * 8 + 4];
        } else {
          bv0 = *(const float4*)&B[(size_t)(k2 + kr) * N + bn * 128 + c4];
          bv1 = *(const float4*)&B[(size_t)(k2 + kr + 8) * N + bn * 128 + c4];
        }
      }
    }
    #pragma unroll
    for (int kk = 0; kk < 16; ++kk) {
      const float4 a0 = *(const float4*)&As[p][kk][ty * 8];
      const float4 a1 = *(const float4*)&As[p][kk][ty * 8 + 4];
      const float4 b0 = *(const float4*)&Bs[p][kk][boff];
      const float4 b1 = *(const float4*)&Bs[p][kk][boff + 32];
      const float ar[8] = {a0.x, a0.y, a0.z, a0.w, a1.x, a1.y, a1.z, a1.w};
      const float br[8] = {b0.x, b0.y, b0.z, b0.w, b1.x, b1.y, b1.z, b1.w};
      #pragma unroll
      for (int r = 0; r < 8; ++r)
        #pragma unroll
        for (int c = 0; c < 8; ++c) acc[r][c] = fmaf(ar[r], br[c], acc[r][c]);
    }
    __syncthreads();
  }

  const int gcol = bn * 128 + tx * 8;
  float bb[8] = {0, 0, 0, 0, 0, 0, 0, 0};
  if (bias) {
    const float4 v0 = *(const float4*)&bias[gcol];
    const float4 v1 = *(const float4*)&bias[gcol + 4];
    bb[0] = v0.x; bb[1] = v0.y; bb[2] = v0.z; bb[3] = v0.w;
    bb[4] = v1.x; bb[5] = v1.y; bb[6] = v1.z; bb[7] = v1.w;
  }
  #pragma unroll
  for (int r = 0; r < 8; ++r) {
    float* cp = &C[(size_t)(bm * 128 + ty * 8 + r) * N + gcol];
    float4 o0, o1;
    o0.x = acc[r][0] + bb[0]; o0.y = acc[r][1] + bb[1];
    o0.z = acc[r][2] + bb[2]; o0.w = acc[r][3] + bb[3];
    o1.x = acc[r][4] + bb[4]; o1.y = acc[r][5] + bb[5];
    o1.z = acc[r][6] + bb[6]; o1.w = acc[r][7] + bb[7];
    *(float4*)cp = o0;
    *(float4*)(cp + 4) = o1;
  }
}

// ---------------------------------------------------------------------------
// OpenBLAS-emulating GEMM (bit-exact chains), 128x128 / 8x8, dbuf (r11 PASSED)
// + optional fused bf16x2 packed-split output (ZP != nullptr).
// ---------------------------------------------------------------------------
__global__ __launch_bounds__(256) void emul_gemm_kernel(
    const float* __restrict__ A, const float* __restrict__ B,
    const float* __restrict__ bias, float* __restrict__ C,
    unsigned* __restrict__ ZP,
    int N, int K, int lda, int ldb, unsigned long long panel_mask) {
  __shared__ float As_[2][32][128];
  __shared__ float Bs_[2][32][128];
  const int tid = threadIdx.x;
  const int tx = tid & 15, ty = tid >> 4;
  const int row0 = blockIdx.y * 128, col0 = blockIdx.x * 128;
  const int sr = tid & 127, sh = tid >> 7;
  const int scol = (((sr >> 2) & 1) << 6) + ((sr >> 3) << 2) + (sr & 3);

  float part[8][8], total[8][8];
  #pragma unroll
  for (int r = 0; r < 8; ++r)
    #pragma unroll
    for (int e = 0; e < 8; ++e) { part[r][e] = 0.f; total[r][e] = 0.f; }

  float4 av[4], bv[4];
  #pragma unroll
  for (int q = 0; q < 4; ++q) {
    av[q] = *(const float4*)&A[(size_t)(row0 + sr) * lda + sh * 16 + q * 4];
    bv[q] = *(const float4*)&B[(size_t)(col0 + sr) * ldb + sh * 16 + q * 4];
  }
  #pragma unroll
  for (int q = 0; q < 4; ++q) {
    As_[0][sh * 16 + q * 4 + 0][sr] = av[q].x;
    As_[0][sh * 16 + q * 4 + 1][sr] = av[q].y;
    As_[0][sh * 16 + q * 4 + 2][sr] = av[q].z;
    As_[0][sh * 16 + q * 4 + 3][sr] = av[q].w;
    Bs_[0][sh * 16 + q * 4 + 0][scol] = bv[q].x;
    Bs_[0][sh * 16 + q * 4 + 1][scol] = bv[q].y;
    Bs_[0][sh * 16 + q * 4 + 2][scol] = bv[q].z;
    Bs_[0][sh * 16 + q * 4 + 3][scol] = bv[q].w;
  }
  const int nch = K >> 5;
  if (nch > 1) {
    #pragma unroll
    for (int q = 0; q < 4; ++q) {
      av[q] = *(const float4*)&A[(size_t)(row0 + sr) * lda + 32 + sh * 16 + q * 4];
      bv[q] = *(const float4*)&B[(size_t)(col0 + sr) * ldb + 32 + sh * 16 + q * 4];
    }
  }
  __syncthreads();

  for (int ci = 0; ci < nch; ++ci) {
    const int p = ci & 1;
    if (ci + 1 < nch) {
      #pragma unroll
      for (int q = 0; q < 4; ++q) {
        As_[p ^ 1][sh * 16 + q * 4 + 0][sr] = av[q].x;
        As_[p ^ 1][sh * 16 + q * 4 + 1][sr] = av[q].y;
        As_[p ^ 1][sh * 16 + q * 4 + 2][sr] = av[q].z;
        As_[p ^ 1][sh * 16 + q * 4 + 3][sr] = av[q].w;
        Bs_[p ^ 1][sh * 16 + q * 4 + 0][scol] = bv[q].x;
        Bs_[p ^ 1][sh * 16 + q * 4 + 1][scol] = bv[q].y;
        Bs_[p ^ 1][sh * 16 + q * 4 + 2][scol] = bv[q].z;
        Bs_[p ^ 1][sh * 16 + q * 4 + 3][scol] = bv[q].w;
      }
      if (ci + 2 < nch) {
        const int k2 = (ci + 2) << 5;
        #pragma unroll
        for (int q = 0; q < 4; ++q) {
          av[q] = *(const float4*)&A[(size_t)(row0 + sr) * lda + k2 + sh * 16 + q * 4];
          bv[q] = *(const float4*)&B[(size_t)(col0 + sr) * ldb + k2 + sh * 16 + q * 4];
        }
      }
    }
    if (ci && ((panel_mask >> ci) & 1ULL)) {
      #pragma unroll
      for (int r = 0; r < 8; ++r)
        #pragma unroll
        for (int e = 0; e < 8; ++e) { total[r][e] = total[r][e] + part[r][e]; part[r][e] = 0.f; }
    }
    #pragma unroll 4
    for (int kk = 0; kk < 32; ++kk) {
      const float4 za = *(const float4*)&As_[p][kk][ty * 8];
      const float4 zb = *(const float4*)&As_[p][kk][ty * 8 + 4];
      const float4 ca = *(const float4*)&Bs_[p][kk][tx * 4];
      const float4 cb4 = *(const float4*)&Bs_[p][kk][64 + tx * 4];
      const float zr[8] = {za.x, za.y, za.z, za.w, zb.x, zb.y, zb.z, zb.w};
      const float cr[8] = {ca.x, ca.y, ca.z, ca.w, cb4.x, cb4.y, cb4.z, cb4.w};
      #pragma unroll
      for (int r = 0; r < 8; ++r)
        #pragma unroll
        for (int e = 0; e < 8; ++e)
          part[r][e] = __builtin_fmaf(zr[r], cr[e], part[r][e]);
    }
    __syncthreads();
  }
  #pragma unroll
  for (int r = 0; r < 8; ++r)
    #pragma unroll
    for (int e = 0; e < 8; ++e) total[r][e] = total[r][e] + part[r][e];

  const float4 ba = *(const float4*)&bias[col0 + tx * 8];
  const float4 bb = *(const float4*)&bias[col0 + tx * 8 + 4];
  const float br8[8] = {ba.x, ba.y, ba.z, ba.w, bb.x, bb.y, bb.z, bb.w};
  #pragma unroll
  for (int r = 0; r < 8; ++r) {
    const size_t rowi = (size_t)(row0 + ty * 8 + r);
    float ov[8];
    #pragma unroll
    for (int j = 0; j < 8; ++j) ov[j] = total[r][j] + br8[j];
    float* cp = &C[rowi * N + col0 + tx * 8];
    float4 o0, o1;
    o0.x = ov[0]; o0.y = ov[1]; o0.z = ov[2]; o0.w = ov[3];
    o1.x = ov[4]; o1.y = ov[5]; o1.z = ov[6]; o1.w = ov[7];
    *(float4*)cp = o0;
    *(float4*)(cp + 4) = o1;
    if (ZP) {  // fused bf16x2 truncation split, packed
      uint4 p0, p1;
      p0.x = packsplit(ov[0]); p0.y = packsplit(ov[1]);
      p0.z = packsplit(ov[2]); p0.w = packsplit(ov[3]);
      p1.x = packsplit(ov[4]); p1.y = packsplit(ov[5]);
      p1.z = packsplit(ov[6]); p1.w = packsplit(ov[7]);
      unsigned* zp = &ZP[rowi * N + col0 + tx * 8];
      *(uint4*)zp = p0;
      *(uint4*)(zp + 4) = p1;
    }
  }
}

// ---------------------------------------------------------------------------
// bf16x2 MFMA distance screen v3. Block = 128 rows x 128 entries, 4 waves,
// K-stage 64 (256B LDS rows: hi bytes 0..127, lo 128..255; XOR (r&7)<<4).
// Z pre-split (packed u32 from the z-GEMM); CB truncation-split inline.
// Epilogue: wave-shuffle min over tx before one atomicMin per 16-lane group.
// ---------------------------------------------------------------------------
__global__ __launch_bounds__(256) void mfma_screen_kernel(
    const unsigned* __restrict__ ZP, const float* __restrict__ CB,
    const float* __restrict__ Z2, const float* __restrict__ C2,
    uint4* __restrict__ recs) {
  __shared__ unsigned short Zs[128 * 128];  // 32 KB
  __shared__ unsigned short Cs[128 * 128];  // 32 KB
  __shared__ int rowminI[128];
  __shared__ int cnt[128];
  __shared__ unsigned short cand[128][12];
  const int tid = threadIdx.x;
  const int wid = tid >> 6, lane = tid & 63;
  const int e0 = blockIdx.x * 128, row0 = blockIdx.y * 128;
  const int wr = (wid >> 1) * 64, wc = (wid & 1) * 64;

  if (tid < 128) { rowminI[tid] = 0x7F800000; cnt[tid] = 0; }

  f32x4 acc[4][4];
  #pragma unroll
  for (int m = 0; m < 4; ++m)
    #pragma unroll
    for (int n = 0; n < 4; ++n)
      #pragma unroll
      for (int j = 0; j < 4; ++j) acc[m][n][j] = 0.f;

  const int stg_r = tid >> 4;         // 0..15
  const int stg_k4 = (tid & 15) * 4;  // 0..60

  for (int k0 = 0; k0 < 1024; k0 += 64) {
    __syncthreads();
    #pragma unroll
    for (int s = 0; s < 8; ++s) {
      const int r = stg_r + s * 16;
      const int swz = (r & 7) << 4;
      const int bhi = (r * 256 + stg_k4 * 2) ^ swz;
      const int blo = (r * 256 + 128 + stg_k4 * 2) ^ swz;
      const uint4 p = *(const uint4*)&ZP[(size_t)(row0 + r) * 1024 + k0 + stg_k4];
      uint2 zh, zl;
      zh.x = (p.x & 0xFFFFu) | (p.y << 16);
      zh.y = (p.z & 0xFFFFu) | (p.w << 16);
      zl.x = (p.x >> 16) | (p.y & 0xFFFF0000u);
      zl.y = (p.z >> 16) | (p.w & 0xFFFF0000u);
      *(uint2*)((char*)Zs + bhi) = zh;
      *(uint2*)((char*)Zs + blo) = zl;
      const float4 cv = *(const float4*)&CB[(size_t)(e0 + r) * 1024 + k0 + stg_k4];
      const float cf[4] = {cv.x, cv.y, cv.z, cv.w};
      unsigned ch[4], cl[4];
      #pragma unroll
      for (int i = 0; i < 4; ++i) {
        const unsigned u = __float_as_uint(cf[i]);
        ch[i] = u & 0xFFFF0000u;
        const float rem = cf[i] - __uint_as_float(ch[i]);
        cl[i] = __float_as_uint(rem) & 0xFFFF0000u;
      }
      uint2 cph, cpl;
      cph.x = (ch[0] >> 16) | ch[1];
      cph.y = (ch[2] >> 16) | ch[3];
      cpl.x = (cl[0] >> 16) | cl[1];
      cpl.y = (cl[2] >> 16) | cl[3];
      *(uint2*)((char*)Cs + bhi) = cph;
      *(uint2*)((char*)Cs + blo) = cpl;
    }
    __syncthreads();
    #pragma unroll
    for (int kh = 0; kh < 2; ++kh) {
      const int kb = kh * 64 + 16 * (lane >> 4);
      short8 ah[4], al[4], bh[4], bl[4];
      #pragma unroll
      for (int m = 0; m < 4; ++m) {
        const int r = wr + m * 16 + (lane & 15);
        const int swz = (r & 7) << 4;
        ah[m] = *(const short8*)((const char*)Zs + ((r * 256 + kb) ^ swz));
        al[m] = *(const short8*)((const char*)Zs + ((r * 256 + 128 + kb) ^ swz));
      }
      #pragma unroll
      for (int n = 0; n < 4; ++n) {
        const int r = wc + n * 16 + (lane & 15);
        const int swz = (r & 7) << 4;
        bh[n] = *(const short8*)((const char*)Cs + ((r * 256 + kb) ^ swz));
        bl[n] = *(const short8*)((const char*)Cs + ((r * 256 + 128 + kb) ^ swz));
      }
      #pragma unroll
      for (int m = 0; m < 4; ++m)
        #pragma unroll
        for (int n = 0; n < 4; ++n) {
          acc[m][n] = __builtin_amdgcn_mfma_f32_16x16x32_bf16(ah[m], bh[n], acc[m][n], 0, 0, 0);
          acc[m][n] = __builtin_amdgcn_mfma_f32_16x16x32_bf16(ah[m], bl[n], acc[m][n], 0, 0, 0);
          acc[m][n] = __builtin_amdgcn_mfma_f32_16x16x32_bf16(al[m], bh[n], acc[m][n], 0, 0, 0);
        }
    }
  }

  // epilogue: d~ values; per-row min via tx-group shuffle then one atomicMin
  float dv[4][4][4];
  #pragma unroll
  for (int m = 0; m < 4; ++m)
    #pragma unroll
    for (int j = 0; j < 4; ++j) {
      const int rg = row0 + wr + m * 16 + (lane >> 4) * 4 + j;
      const float z2r = Z2[rg];
      float lm = FLT_MAX;
      #pragma unroll
      for (int n = 0; n < 4; ++n) {
        const float d = __builtin_fmaf(-2.0f, acc[m][n][j], z2r) +
                        C2[e0 + wc + n * 16 + (lane & 15)];
        dv[m][n][j] = d;
        lm = fminf(lm, d);
      }
      #pragma unroll
      for (int msk = 1; msk < 16; msk <<= 1)
        lm = fminf(lm, __shfl_xor(lm, msk, 64));
      if ((lane & 15) == 0)
        atomicMin(&rowminI[wr + m * 16 + (lane >> 4) * 4 + j], __float_as_int(lm));
    }
  __syncthreads();
  #pragma unroll
  for (int m = 0; m < 4; ++m)
    #pragma unroll
    for (int j = 0; j < 4; ++j) {
      const int rl = wr + m * 16 + (lane >> 4) * 4 + j;
      const float thr = __int_as_float(rowminI[rl]) + SCREEN_DELTA;
      #pragma unroll
      for (int n = 0; n < 4; ++n) {
        if (dv[m][n][j] <= thr) {
          const int pos = atomicAdd(&cnt[rl], 1);
          if (pos < 12)
            cand[rl][pos] = (unsigned short)(e0 + wc + n * 16 + (lane & 15));
        }
      }
    }
  __syncthreads();
  if (tid < 128) {
    uint4 a, b;
    a.x = (unsigned)rowminI[tid];
    a.y = (unsigned)cnt[tid];
    a.z = (unsigned)cand[tid][0] | ((unsigned)cand[tid][1] << 16);
    a.w = (unsigned)cand[tid][2] | ((unsigned)cand[tid][3] << 16);
    b.x = (unsigned)cand[tid][4] | ((unsigned)cand[tid][5] << 16);
    b.y = (unsigned)cand[tid][6] | ((unsigned)cand[tid][7] << 16);
    b.z = (unsigned)cand[tid][8] | ((unsigned)cand[tid][9] << 16);
    b.w = (unsigned)cand[tid][10] | ((unsigned)cand[tid][11] << 16);
    const size_t base = ((size_t)(row0 + tid) * 64 + blockIdx.x) * 2;
    recs[base] = a;
    recs[base + 1] = b;
  }
}

// ---------------------------------------------------------------------------
// Collect + exact rescore + z_q gather + embedding partial. Block per row.
// ---------------------------------------------------------------------------
__global__ __launch_bounds__(256) void collect_rescore_kernel(
    const uint4* __restrict__ recs, const float* __restrict__ Z,
    const float* __restrict__ CB, const float* __restrict__ Z2,
    const float* __restrict__ C2, int* __restrict__ ids,
    float* __restrict__ o_ids, float* __restrict__ o_zq,
    float* __restrict__ esum) {
  __shared__ float zsh[1024];
  __shared__ float gmin_sh;
  __shared__ int lcnt, ovf, ewin;
  __shared__ unsigned short list[64];
  __shared__ unsigned long long kred[4];
  const int row = blockIdx.x, tid = threadIdx.x;
  if (tid == 0) { lcnt = 0; ovf = 0; }
  uint4 r0 = make_uint4(0, 0, 0, 0), r1 = make_uint4(0, 0, 0, 0);
  float mymin = FLT_MAX;
  if (tid < 64) {
    const size_t base = ((size_t)row * 64 + tid) * 2;
    r0 = recs[base];
    r1 = recs[base + 1];
    mymin = __uint_as_float(r0.x);
  }
  for (int i = tid; i < 1024; i += 256) zsh[i] = Z[(size_t)row * 1024 + i];
  if (tid < 64) {
    float m = mymin;
    #pragma unroll
    for (int off = 32; off > 0; off >>= 1) m = fminf(m, __shfl_down(m, off, 64));
    if (tid == 0) gmin_sh = m;
  }
  __syncthreads();
  const float thr = gmin_sh + SCREEN_DELTA;
  if (tid < 64 && mymin <= thr) {
    const int c = (int)r0.y;
    if (c > 12) {
      atomicOr(&ovf, 1);
    } else {
      unsigned short idxs[12];
      idxs[0] = r0.z & 0xFFFF; idxs[1] = r0.z >> 16;
      idxs[2] = r0.w & 0xFFFF; idxs[3] = r0.w >> 16;
      idxs[4] = r1.x & 0xFFFF; idxs[5] = r1.x >> 16;
      idxs[6] = r1.y & 0xFFFF; idxs[7] = r1.y >> 16;
      idxs[8] = r1.z & 0xFFFF; idxs[9] = r1.z >> 16;
      idxs[10] = r1.w & 0xFFFF; idxs[11] = r1.w >> 16;
      for (int i = 0; i < c; ++i) {
        const int pos = atomicAdd(&lcnt, 1);
        if (pos < 64) list[pos] = idxs[i];
        else atomicOr(&ovf, 1);
      }
    }
  }
  __syncthreads();
  const float z2r = Z2[row];
  unsigned long long key = ~0ULL;
  if (ovf) {  // rare: exact full-row scan
    for (int e = tid; e < CBK; e += 256) {
      const float d = chain_d(zsh, &CB[(size_t)e * 1024], z2r, C2[e]);
      const unsigned long long k =
          ((unsigned long long)__float_as_uint(d) << 32) | (unsigned)e;
      key = (k < key) ? k : key;
    }
  } else {
    const int n = lcnt < 64 ? lcnt : 64;
    if (tid < n) {
      const int e = list[tid];
      const float d = chain_d(zsh, &CB[(size_t)e * 1024], z2r, C2[e]);
      key = ((unsigned long long)__float_as_uint(d) << 32) | (unsigned)e;
    }
  }
  #pragma unroll
  for (int off = 32; off > 0; off >>= 1) {
    const unsigned long long o = __shfl_down(key, off, 64);
    key = (o < key) ? o : key;
  }
  if ((tid & 63) == 0) kred[tid >> 6] = key;
  __syncthreads();
  if (tid == 0) {
    unsigned long long k = kred[0];
    k = (kred[1] < k) ? kred[1] : k;
    k = (kred[2] < k) ? kred[2] : k;
    k = (kred[3] < k) ? kred[3] : k;
    const int e = (int)(k & 0xFFFFFFFFu);
    ids[row] = e;
    o_ids[row] = (float)e;
    ewin = e;
  }
  __syncthreads();
  // fused z_q gather + embedding partial (exact z in zsh)
  const int e2 = ewin;
  float s = 0.f;
  for (int i = tid; i < 1024; i += 256) {
    const float c = CB[(size_t)e2 * 1024 + i];
    o_zq[(size_t)row * 1024 + i] = c;
    const float d = zsh[i] - c;
    s = __builtin_fmaf(d, d, s);
  }
  const float r2 = block_reduce_sum(s);
  if (tid == 0) esum[row] = r2;
}

// ---------------------------------------------------------------------------
// bf16 MFMA recon (r11 PASSED, unchanged).
// ---------------------------------------------------------------------------
__global__ __launch_bounds__(256) void mfma_recon_kernel(
    const float* __restrict__ A, const float* __restrict__ B,
    const float* __restrict__ bias, float* __restrict__ C) {
  __shared__ unsigned short Abf[128 * 64];
  __shared__ unsigned short Bbf[128 * 64];
  const int tid = threadIdx.x;
  const int wid = tid >> 6, lane = tid & 63;
  const int row0 = blockIdx.y * 128, col0 = blockIdx.x * 128;
  const int wr = (wid >> 1) * 64, wc = (wid & 1) * 64;

  f32x4 acc[4][4];
  #pragma unroll
  for (int m = 0; m < 4; ++m)
    #pragma unroll
    for (int n = 0; n < 4; ++n)
      #pragma unroll
      for (int j = 0; j < 4; ++j) acc[m][n][j] = 0.f;

  for (int k0 = 0; k0 < 1024; k0 += 64) {
    __syncthreads();
    #pragma unroll
    for (int q = 0; q < 4; ++q) {
      const int g = tid + q * 256;
      const int r = g >> 3;
      const int kg = (g & 7) * 8;
      const float4 a0 = *(const float4*)&A[(size_t)(row0 + r) * 1024 + k0 + kg];
      const float4 a1 = *(const float4*)&A[(size_t)(row0 + r) * 1024 + k0 + kg + 4];
      const float4 b0 = *(const float4*)&B[(size_t)(col0 + r) * 1024 + k0 + kg];
      const float4 b1 = *(const float4*)&B[(size_t)(col0 + r) * 1024 + k0 + kg + 4];
      ushort8 pa, pb;
      pa[0] = f2bf(a0.x); pa[1] = f2bf(a0.y); pa[2] = f2bf(a0.z); pa[3] = f2bf(a0.w);
      pa[4] = f2bf(a1.x); pa[5] = f2bf(a1.y); pa[6] = f2bf(a1.z); pa[7] = f2bf(a1.w);
      pb[0] = f2bf(b0.x); pb[1] = f2bf(b0.y); pb[2] = f2bf(b0.z); pb[3] = f2bf(b0.w);
      pb[4] = f2bf(b1.x); pb[5] = f2bf(b1.y); pb[6] = f2bf(b1.z); pb[7] = f2bf(b1.w);
      const int byte = (r * 128 + kg * 2) ^ ((r & 7) << 4);
      *(ushort8*)((char*)Abf + byte) = pa;
      *(ushort8*)((char*)Bbf + byte) = pb;
    }
    __syncthreads();
    #pragma unroll
    for (int kh = 0; kh < 2; ++kh) {
      const int kb = kh * 32 + 8 * (lane >> 4);
      short8 afr[4], bfr[4];
      #pragma unroll
      for (int m = 0; m < 4; ++m) {
        const int r = wr + m * 16 + (lane & 15);
        const int byte = (r * 128 + kb * 2) ^ ((r & 7) << 4);
        afr[m] = *(const short8*)((const char*)Abf + byte);
      }
      #pragma unroll
      for (int n = 0; n < 4; ++n) {
        const int r = wc + n * 16 + (lane & 15);
        const int byte = (r * 128 + kb * 2) ^ ((r & 7) << 4);
        bfr[n] = *(const short8*)((const char*)Bbf + byte);
      }
      #pragma unroll
      for (int m = 0; m < 4; ++m)
        #pragma unroll
        for (int n = 0; n < 4; ++n)
          acc[m][n] = __builtin_amdgcn_mfma_f32_16x16x32_bf16(
              afr[m], bfr[n], acc[m][n], 0, 0, 0);
    }
  }

  #pragma unroll
  for (int m = 0; m < 4; ++m)
    #pragma unroll
    for (int n = 0; n < 4; ++n) {
      const int col = col0 + wc + n * 16 + (lane & 15);
      const float bc = bias[col];
      #pragma unroll
      for (int j = 0; j < 4; ++j) {
        const int row = row0 + wr + m * 16 + (lane >> 4) * 4 + j;
        C[(size_t)row * 2048 + col] = acc[m][n][j] + bc;
      }
    }
}

// ---------------------------------------------------------------------------
// numpy pairwise_sum emulation of sum(x*x) over rows of 1024 (unchanged).
// ---------------------------------------------------------------------------
__global__ __launch_bounds__(256) void sumsq1024_kernel(
    const float* __restrict__ X, float* __restrict__ out) {
  __shared__ float rows[4][1024];
  __shared__ float leaves[4][8];
  const int tid = threadIdx.x;
  const int row0 = blockIdx.x * 4;
  for (int i = tid; i < 4096; i += 256)
    rows[i >> 10][i & 1023] = X[(size_t)row0 * 1024 + i];
  __syncthreads();
  if (tid < 32) {
    const int r = tid >> 3, lf = tid & 7;
    const float* a = &rows[r][lf * 128];
    float s0 = sqf(a[0]), s1 = sqf(a[1]), s2 = sqf(a[2]), s3 = sqf(a[3]);
    float s4 = sqf(a[4]), s5 = sqf(a[5]), s6 = sqf(a[6]), s7 = sqf(a[7]);
    for (int i = 8; i < 128; i += 8) {
      s0 = s0 + sqf(a[i + 0]); s1 = s1 + sqf(a[i + 1]);
      s2 = s2 + sqf(a[i + 2]); s3 = s3 + sqf(a[i + 3]);
      s4 = s4 + sqf(a[i + 4]); s5 = s5 + sqf(a[i + 5]);
      s6 = s6 + sqf(a[i + 6]); s7 = s7 + sqf(a[i + 7]);
    }
    leaves[r][lf] = ((s0 + s1) + (s2 + s3)) + ((s4 + s5) + (s6 + s7));
  }
  __syncthreads();
  if (tid < 4) {
    const float* L = leaves[tid];
    const float p01 = L[0] + L[1], p23 = L[2] + L[3];
    const float p45 = L[4] + L[5], p67 = L[6] + L[7];
    out[row0 + tid] = ((p01 + p23) + (p45 + p67));
  }
}

__global__ __launch_bounds__(256) void rowdot_bias_kernel(
    const float* __restrict__ W, const float* __restrict__ v,
    const float* __restrict__ b2, float* __restrict__ out) {
  const int row = blockIdx.x;
  const float4 w4 = *(const float4*)&W[(size_t)row * 1024 + threadIdx.x * 4];
  const float4 v4 = *(const float4*)&v[threadIdx.x * 4];
  const float s = w4.x * v4.x + w4.y * v4.y + w4.z * v4.z + w4.w * v4.w;
  const float r = block_reduce_sum(s);
  if (threadIdx.x == 0) out[row] = r + b2[row];
}

__global__ __launch_bounds__(256) void sqdiff_partial_kernel(
    const float* __restrict__ a, const float* __restrict__ b,
    float* __restrict__ part) {
  const size_t base = (size_t)blockIdx.x * 2048 + (size_t)threadIdx.x * 8;
  const float4 x0 = *(const float4*)&a[base];
  const float4 x1 = *(const float4*)&a[base + 4];
  const float4 y0 = *(const float4*)&b[base];
  const float4 y1 = *(const float4*)&b[base + 4];
  float s = 0.f;
  float d;
  d = x0.x - y0.x; s += d * d; d = x0.y - y0.y; s += d * d;
  d = x0.z - y0.z; s += d * d; d = x0.w - y0.w; s += d * d;
  d = x1.x - y1.x; s += d * d; d = x1.y - y1.y; s += d * d;
  d = x1.z - y1.z; s += d * d; d = x1.w - y1.w; s += d * d;
  const float r = block_reduce_sum(s);
  if (threadIdx.x == 0) part[blockIdx.x] = r;
}

__global__ __launch_bounds__(256) void final_losses_kernel(
    const float* __restrict__ rp, const float* __restrict__ esum,
    float* __restrict__ o) {
  __shared__ double sh[4];
  const int lane = threadIdx.x & 63, w = threadIdx.x >> 6;
  double s = 0.0;
  for (int i = threadIdx.x; i < 8192; i += 256) s += (double)rp[i];
  #pragma unroll
  for (int off = 32; off > 0; off >>= 1) s += __shfl_down(s, off, 64);
  if (lane == 0) sh[w] = s;
  __syncthreads();
  double rl = 0.0;
  if (threadIdx.x == 0) rl = (sh[0] + sh[1] + sh[2] + sh[3]) / ((double)N_ROWS * IN_DIM);
  __syncthreads();
  double s2 = 0.0;
  for (int i = threadIdx.x; i < 8192; i += 256) s2 += (double)esum[i];
  #pragma unroll
  for (int off = 32; off > 0; off >>= 1) s2 += __shfl_down(s2, off, 64);
  if (lane == 0) sh[w] = s2;
  __syncthreads();
  if (threadIdx.x == 0) {
    const double el = (sh[0] + sh[1] + sh[2] + sh[3]) / ((double)N_ROWS * DIM);
    o[0] = (float)(rl + el + 0.25 * el);
    o[1] = (float)rl;
    o[2] = (float)el;
    o[3] = (float)el;
  }
}

extern "C" void kernel_launch(void* const* d_in, const int* in_sizes, int n_in,
                              void* d_out, int out_size, void* d_ws, size_t ws_size,
                              hipStream_t stream) {
  const float* roi   = (const float*)d_in[0];
  const float* W_in  = (const float*)d_in[1];
  const float* b_in  = (const float*)d_in[2];
  const float* W_enc = (const float*)d_in[3];
  const float* b_enc = (const float*)d_in[4];
  const float* cb    = (const float*)d_in[5];
  const float* W_dec = (const float*)d_in[6];
  const float* b_dec = (const float*)d_in[7];
  const float* W_out = (const float*)d_in[8];
  const float* b_out = (const float*)d_in[9];

  float* out = (float*)d_out;
  float* o_ids   = out;
  float* o_zq    = out + 8192;
  float* o_recon = out + 8192 + (size_t)N_ROWS * DIM;
  float* o_scal  = out + 8192 + (size_t)N_ROWS * DIM + (size_t)N_ROWS * IN_DIM;

  // ws layout (float offsets)
  float*  ws    = (float*)d_ws;
  float*  W_dc  = ws;                          // 2,097,152
  float*  z2    = ws + 2097152;                // 8192
  float*  c2    = ws + 2105344;                // 8192
  int*    ids   = (int*)(ws + 2113536);        // 8192
  float*  b_dc  = ws + 2121728;                // 2048
  float*  esum  = ws + 2123776;                // 8192 (per-row embedding sums)
  float*  rp    = ws + 2131968;                // 8192

  // Scratch reuse:
  //  o_recon (64 MB): t (f32, 1st half) dead after z-GEMM -> recs (16 MB)
  //    live there during screen/collect. z (f32) in 2nd half, live until
  //    collect. recon overwrites everything at the end.
  //  o_zq region (32 MB): zpack (u32 8192x1024, exact fit) written by the
  //    z-GEMM epilogue, consumed by screen; collect then overwrites with z_q.
  float*    t     = o_recon;
  float*    z     = o_recon + (size_t)N_ROWS * DIM;
  uint4*    recs  = (uint4*)o_recon;           // over dead t
  unsigned* zpack = (unsigned*)o_zq;

  // decoder fusion (2%-threshold outputs)
  rowdot_bias_kernel<<<IN_DIM, 256, 0, stream>>>(W_out, b_dec, b_out, b_dc);
  gemm128<false><<<dim3(DIM / 128, IN_DIM / 128), 256, 0, stream>>>(
      W_out, W_dec, nullptr, W_dc, IN_DIM, DIM, DIM);

  // ---- np-f32 emulated encoder (bit-exact chains) ----
  emul_gemm_kernel<<<dim3(DIM / 128, N_ROWS / 128), 256, 0, stream>>>(
      roi, W_in, b_in, t, nullptr, DIM, IN_DIM, IN_DIM, IN_DIM,
      PANEL_MASK_K2048_C32);
  emul_gemm_kernel<<<dim3(DIM / 128, N_ROWS / 128), 256, 0, stream>>>(
      t, W_enc, b_enc, z, zpack, DIM, DIM, DIM, DIM, PANEL_MASK_K1024_C32);

  // ---- np pairwise row sums of squares ----
  sumsq1024_kernel<<<N_ROWS / 4, 256, 0, stream>>>(z, z2);
  sumsq1024_kernel<<<CBK / 4, 256, 0, stream>>>(cb, c2);

  // ---- certified MFMA screen (recs over dead t region) ----
  mfma_screen_kernel<<<dim3(CBK / 128, N_ROWS / 128), 256, 0, stream>>>(
      zpack, cb, z2, c2, recs);
  // ---- exact rescore + z_q gather + embedding partials ----
  collect_rescore_kernel<<<N_ROWS, 256, 0, stream>>>(
      recs, z, cb, z2, c2, ids, o_ids, o_zq, esum);

  // recon via bf16 MFMA (overwrites recs/z region AFTER collect consumed them)
  mfma_recon_kernel<<<dim3(IN_DIM / 128, N_ROWS / 128), 256, 0, stream>>>(
      o_zq, W_dc, b_dc, o_recon);

  sqdiff_partial_kernel<<<(N_ROWS * IN_DIM) / 2048, 256, 0, stream>>>(
      o_recon, roi, rp);
  final_losses_kernel<<<1, 256, 0, stream>>>(rp, esum, o_scal);
}

// Round 16
// 1473.333 us; speedup vs baseline: 1.2633x; 1.2633x over previous
//
#include <hip/hip_runtime.h>
#include <float.h>

// ---------------------------------------------------------------------------
// VQ-VAE quantizer forward — round 16: r15 pipeline with the screen reverted
// to r14's 32-k-stage / 36 KB-LDS geometry (4 blocks/CU; r15's 64-k stage
// halved residency -> both pipes starved). Keeps r15's wins: zsplit fused
// into the z-GEMM (packed bf16x2), shuffle-min epilogue, folded collect
// (z_q gather + embedding partial).
// ids semantics unchanged: certified bf16x2 MFMA screen (DELTA=1.2e-3) +
// exact sequential-k chain rescore (panel joins k=384,704) = np first-index.
// ---------------------------------------------------------------------------

#define N_ROWS 8192
#define IN_DIM 2048
#define DIM 1024
#define CBK 8192

#define PANEL_MASK_K1024_C32 0x0000000000401000ULL  // joins k=384,704
#define PANEL_MASK_K2048_C32 0x0101001001001000ULL  // k=384,768,1152,1536,1792

#define SCREEN_DELTA 1.2e-3f

typedef __attribute__((ext_vector_type(8))) short short8;
typedef __attribute__((ext_vector_type(8))) unsigned short ushort8;
typedef __attribute__((ext_vector_type(4))) float f32x4;

__device__ __forceinline__ float sqf(float v) { return __builtin_fmaf(v, v, 0.0f); }

__device__ __forceinline__ unsigned short f2bf(float f) {  // RNE f32->bf16
  unsigned int u = __float_as_uint(f);
  u += 0x7fffu + ((u >> 16) & 1u);
  return (unsigned short)(u >> 16);
}

// truncation split x = hi + rem; pack (hi>>16) | (trunc_bf16(rem) bits)
__device__ __forceinline__ unsigned packsplit(float x) {
  const unsigned u = __float_as_uint(x);
  const unsigned hb = u & 0xFFFF0000u;
  const float rem = x - __uint_as_float(hb);
  return (u >> 16) | (__float_as_uint(rem) & 0xFFFF0000u);
}

__device__ __forceinline__ int swz128(int c) {
  return (c & 3) | (((c >> 3) & 7) << 2) | (((c >> 2) & 1) << 5) | ((c >> 6) << 6);
}

__device__ __forceinline__ float block_reduce_sum(float v) {
  __shared__ float sh[4];
  #pragma unroll
  for (int off = 32; off > 0; off >>= 1) v += __shfl_down(v, off, 64);
  const int lane = threadIdx.x & 63, w = threadIdx.x >> 6;
  if (lane == 0) sh[w] = v;
  __syncthreads();
  float r = 0.f;
  if (threadIdx.x == 0) r = sh[0] + sh[1] + sh[2] + sh[3];
  return r;  // valid on thread 0 only
}

// exact emulated-f32 distance: sequential-k chain, panel joins at 384/704.
__device__ __forceinline__ float chain_d(const float* __restrict__ zsh,
                                         const float* __restrict__ cbr,
                                         float z2r, float c2e) {
  float part = 0.f;
  for (int k = 0; k < 384; ++k) part = __builtin_fmaf(zsh[k], cbr[k], part);
  float total = part;
  part = 0.f;
  for (int k = 384; k < 704; ++k) part = __builtin_fmaf(zsh[k], cbr[k], part);
  total = total + part;
  part = 0.f;
  for (int k = 704; k < 1024; ++k) part = __builtin_fmaf(zsh[k], cbr[k], part);
  total = total + part;
  return __builtin_fmaf(-2.0f, total, z2r) + c2e;
}

// ---------------------------------------------------------------------------
// fp32 128x128x16 tiled GEMM (W_dc fusion only). Double-buffered. (r10 PASSED)
// ---------------------------------------------------------------------------
template <bool BT>
__global__ __launch_bounds__(256) void gemm128(
    const float* __restrict__ A, const float* __restrict__ B,
    const float* __restrict__ bias, float* __restrict__ C,
    int M, int N, int K) {
  __shared__ float As[2][16][132];
  __shared__ float Bs[2][16][132];
  const int tid = threadIdx.x;
  const int tx = tid & 15, ty = tid >> 4;
  const int bm = blockIdx.y, bn = blockIdx.x;

  const int mload = tid & 127, kh = tid >> 7;
  const size_t arow = (size_t)(bm * 128 + mload) * (size_t)K;
  const size_t brow = BT ? (size_t)(bn * 128 + mload) * (size_t)K : 0;
  const int swn = swz128(mload);
  const int c4 = (tid & 31) << 2;
  const int kr = tid >> 5;
  const int swc = swz128(c4);

  float acc[8][8];
  #pragma unroll
  for (int r = 0; r < 8; ++r)
    #pragma unroll
    for (int c = 0; c < 8; ++c) acc[r][c] = 0.f;

  const int boff = ((tx & 7) << 2) | ((tx >> 3) << 6);

  float4 av0, av1, bv0, bv1;
  av0 = *(const float4*)&A[arow + kh * 8];
  av1 = *(const float4*)&A[arow + kh * 8 + 4];
  if (BT) {
    bv0 = *(const float4*)&B[brow + kh * 8];
    bv1 = *(const float4*)&B[brow + kh * 8 + 4];
  } else {
    bv0 = *(const float4*)&B[(size_t)kr * N + bn * 128 + c4];
    bv1 = *(const float4*)&B[(size_t)(kr + 8) * N + bn * 128 + c4];
  }
  As[0][kh * 8 + 0][mload] = av0.x; As[0][kh * 8 + 1][mload] = av0.y;
  As[0][kh * 8 + 2][mload] = av0.z; As[0][kh * 8 + 3][mload] = av0.w;
  As[0][kh * 8 + 4][mload] = av1.x; As[0][kh * 8 + 5][mload] = av1.y;
  As[0][kh * 8 + 6][mload] = av1.z; As[0][kh * 8 + 7][mload] = av1.w;
  if (BT) {
    Bs[0][kh * 8 + 0][swn] = bv0.x; Bs[0][kh * 8 + 1][swn] = bv0.y;
    Bs[0][kh * 8 + 2][swn] = bv0.z; Bs[0][kh * 8 + 3][swn] = bv0.w;
    Bs[0][kh * 8 + 4][swn] = bv1.x; Bs[0][kh * 8 + 5][swn] = bv1.y;
    Bs[0][kh * 8 + 6][swn] = bv1.z; Bs[0][kh * 8 + 7][swn] = bv1.w;
  } else {
    *(float4*)&Bs[0][kr][swc] = bv0;
    *(float4*)&Bs[0][kr + 8][swc] = bv1;
  }
  const int nk = K >> 4;
  if (nk > 1) {
    av0 = *(const float4*)&A[arow + 16 + kh * 8];
    av1 = *(const float4*)&A[arow + 16 + kh * 8 + 4];
    if (BT) {
      bv0 = *(const float4*)&B[brow + 16 + kh * 8];
      bv1 = *(const float4*)&B[brow + 16 + kh * 8 + 4];
    } else {
      bv0 = *(const float4*)&B[(size_t)(16 + kr) * N + bn * 128 + c4];
      bv1 = *(const float4*)&B[(size_t)(16 + kr + 8) * N + bn * 128 + c4];
    }
  }
  __syncthreads();

  for (int ki = 0; ki < nk; ++ki) {
    const int p = ki & 1;
    if (ki + 1 < nk) {
      As[p ^ 1][kh * 8 + 0][mload] = av0.x; As[p ^ 1][kh * 8 + 1][mload] = av0.y;
      As[p ^ 1][kh * 8 + 2][mload] = av0.z; As[p ^ 1][kh * 8 + 3][mload] = av0.w;
      As[p ^ 1][kh * 8 + 4][mload] = av1.x; As[p ^ 1][kh * 8 + 5][mload] = av1.y;
      As[p ^ 1][kh * 8 + 6][mload] = av1.z; As[p ^ 1][kh * 8 + 7][mload] = av1.w;
      if (BT) {
        Bs[p ^ 1][kh * 8 + 0][swn] = bv0.x; Bs[p ^ 1][kh * 8 + 1][swn] = bv0.y;
        Bs[p ^ 1][kh * 8 + 2][swn] = bv0.z; Bs[p ^ 1][kh * 8 + 3][swn] = bv0.w;
        Bs[p ^ 1][kh * 8 + 4][swn] = bv1.x; Bs[p ^ 1][kh * 8 + 5][swn] = bv1.y;
        Bs[p ^ 1][kh * 8 + 6][swn] = bv1.z; Bs[p ^ 1][kh * 8 + 7][swn] = bv1.w;
      } else {
        *(float4*)&Bs[p ^ 1][kr][swc] = bv0;
        *(float4*)&Bs[p ^ 1][kr + 8][swc] = bv1;
      }
      if (ki + 2 < nk) {
        const int k2 = (ki + 2) << 4;
        av0 = *(const float4*)&A[arow + k2 + kh * 8];
        av1 = *(const float4*)&A[arow + k2 + kh * 8 + 4];
        if (BT) {
          bv0 = *(const float4*)&B[brow + k2 + kh * 8];
          bv1 = *(const float4*)&B[brow + k2 + kh * 8 + 4];
        } else {
          bv0 = *(const float4*)&B[(size_t)(k2 + kr) * N + bn * 128 + c4];
          bv1 = *(const float4*)&B[(size_t)(k2 + kr + 8) * N + bn * 128 + c4];
        }
      }
    }
    #pragma unroll
    for (int kk = 0; kk < 16; ++kk) {
      const float4 a0 = *(const float4*)&As[p][kk][ty * 8];
      const float4 a1 = *(const float4*)&As[p][kk][ty * 8 + 4];
      const float4 b0 = *(const float4*)&Bs[p][kk][boff];
      const float4 b1 = *(const float4*)&Bs[p][kk][boff + 32];
      const float ar[8] = {a0.x, a0.y, a0.z, a0.w, a1.x, a1.y, a1.z, a1.w};
      const float br[8] = {b0.x, b0.y, b0.z, b0.w, b1.x, b1.y, b1.z, b1.w};
      #pragma unroll
      for (int r = 0; r < 8; ++r)
        #pragma unroll
        for (int c = 0; c < 8; ++c) acc[r][c] = fmaf(ar[r], br[c], acc[r][c]);
    }
    __syncthreads();
  }

  const int gcol = bn * 128 + tx * 8;
  float bb[8] = {0, 0, 0, 0, 0, 0, 0, 0};
  if (bias) {
    const float4 v0 = *(const float4*)&bias[gcol];
    const float4 v1 = *(const float4*)&bias[gcol + 4];
    bb[0] = v0.x; bb[1] = v0.y; bb[2] = v0.z; bb[3] = v0.w;
    bb[4] = v1.x; bb[5] = v1.y; bb[6] = v1.z; bb[7] = v1.w;
  }
  #pragma unroll
  for (int r = 0; r < 8; ++r) {
    float* cp = &C[(size_t)(bm * 128 + ty * 8 + r) * N + gcol];
    float4 o0, o1;
    o0.x = acc[r][0] + bb[0]; o0.y = acc[r][1] + bb[1];
    o0.z = acc[r][2] + bb[2]; o0.w = acc[r][3] + bb[3];
    o1.x = acc[r][4] + bb[4]; o1.y = acc[r][5] + bb[5];
    o1.z = acc[r][6] + bb[6]; o1.w = acc[r][7] + bb[7];
    *(float4*)cp = o0;
    *(float4*)(cp + 4) = o1;
  }
}

// ---------------------------------------------------------------------------
// OpenBLAS-emulating GEMM (bit-exact chains), 128x128 / 8x8, dbuf (r11 PASSED)
// + optional fused bf16x2 packed-split output (ZP != nullptr).
// ---------------------------------------------------------------------------
__global__ __launch_bounds__(256) void emul_gemm_kernel(
    const float* __restrict__ A, const float* __restrict__ B,
    const float* __restrict__ bias, float* __restrict__ C,
    unsigned* __restrict__ ZP,
    int N, int K, int lda, int ldb, unsigned long long panel_mask) {
  __shared__ float As_[2][32][128];
  __shared__ float Bs_[2][32][128];
  const int tid = threadIdx.x;
  const int tx = tid & 15, ty = tid >> 4;
  const int row0 = blockIdx.y * 128, col0 = blockIdx.x * 128;
  const int sr = tid & 127, sh = tid >> 7;
  const int scol = (((sr >> 2) & 1) << 6) + ((sr >> 3) << 2) + (sr & 3);

  float part[8][8], total[8][8];
  #pragma unroll
  for (int r = 0; r < 8; ++r)
    #pragma unroll
    for (int e = 0; e < 8; ++e) { part[r][e] = 0.f; total[r][e] = 0.f; }

  float4 av[4], bv[4];
  #pragma unroll
  for (int q = 0; q < 4; ++q) {
    av[q] = *(const float4*)&A[(size_t)(row0 + sr) * lda + sh * 16 + q * 4];
    bv[q] = *(const float4*)&B[(size_t)(col0 + sr) * ldb + sh * 16 + q * 4];
  }
  #pragma unroll
  for (int q = 0; q < 4; ++q) {
    As_[0][sh * 16 + q * 4 + 0][sr] = av[q].x;
    As_[0][sh * 16 + q * 4 + 1][sr] = av[q].y;
    As_[0][sh * 16 + q * 4 + 2][sr] = av[q].z;
    As_[0][sh * 16 + q * 4 + 3][sr] = av[q].w;
    Bs_[0][sh * 16 + q * 4 + 0][scol] = bv[q].x;
    Bs_[0][sh * 16 + q * 4 + 1][scol] = bv[q].y;
    Bs_[0][sh * 16 + q * 4 + 2][scol] = bv[q].z;
    Bs_[0][sh * 16 + q * 4 + 3][scol] = bv[q].w;
  }
  const int nch = K >> 5;
  if (nch > 1) {
    #pragma unroll
    for (int q = 0; q < 4; ++q) {
      av[q] = *(const float4*)&A[(size_t)(row0 + sr) * lda + 32 + sh * 16 + q * 4];
      bv[q] = *(const float4*)&B[(size_t)(col0 + sr) * ldb + 32 + sh * 16 + q * 4];
    }
  }
  __syncthreads();

  for (int ci = 0; ci < nch; ++ci) {
    const int p = ci & 1;
    if (ci + 1 < nch) {
      #pragma unroll
      for (int q = 0; q < 4; ++q) {
        As_[p ^ 1][sh * 16 + q * 4 + 0][sr] = av[q].x;
        As_[p ^ 1][sh * 16 + q * 4 + 1][sr] = av[q].y;
        As_[p ^ 1][sh * 16 + q * 4 + 2][sr] = av[q].z;
        As_[p ^ 1][sh * 16 + q * 4 + 3][sr] = av[q].w;
        Bs_[p ^ 1][sh * 16 + q * 4 + 0][scol] = bv[q].x;
        Bs_[p ^ 1][sh * 16 + q * 4 + 1][scol] = bv[q].y;
        Bs_[p ^ 1][sh * 16 + q * 4 + 2][scol] = bv[q].z;
        Bs_[p ^ 1][sh * 16 + q * 4 + 3][scol] = bv[q].w;
      }
      if (ci + 2 < nch) {
        const int k2 = (ci + 2) << 5;
        #pragma unroll
        for (int q = 0; q < 4; ++q) {
          av[q] = *(const float4*)&A[(size_t)(row0 + sr) * lda + k2 + sh * 16 + q * 4];
          bv[q] = *(const float4*)&B[(size_t)(col0 + sr) * ldb + k2 + sh * 16 + q * 4];
        }
      }
    }
    if (ci && ((panel_mask >> ci) & 1ULL)) {
      #pragma unroll
      for (int r = 0; r < 8; ++r)
        #pragma unroll
        for (int e = 0; e < 8; ++e) { total[r][e] = total[r][e] + part[r][e]; part[r][e] = 0.f; }
    }
    #pragma unroll 4
    for (int kk = 0; kk < 32; ++kk) {
      const float4 za = *(const float4*)&As_[p][kk][ty * 8];
      const float4 zb = *(const float4*)&As_[p][kk][ty * 8 + 4];
      const float4 ca = *(const float4*)&Bs_[p][kk][tx * 4];
      const float4 cb4 = *(const float4*)&Bs_[p][kk][64 + tx * 4];
      const float zr[8] = {za.x, za.y, za.z, za.w, zb.x, zb.y, zb.z, zb.w};
      const float cr[8] = {ca.x, ca.y, ca.z, ca.w, cb4.x, cb4.y, cb4.z, cb4.w};
      #pragma unroll
      for (int r = 0; r < 8; ++r)
        #pragma unroll
        for (int e = 0; e < 8; ++e)
          part[r][e] = __builtin_fmaf(zr[r], cr[e], part[r][e]);
    }
    __syncthreads();
  }
  #pragma unroll
  for (int r = 0; r < 8; ++r)
    #pragma unroll
    for (int e = 0; e < 8; ++e) total[r][e] = total[r][e] + part[r][e];

  const float4 ba = *(const float4*)&bias[col0 + tx * 8];
  const float4 bb = *(const float4*)&bias[col0 + tx * 8 + 4];
  const float br8[8] = {ba.x, ba.y, ba.z, ba.w, bb.x, bb.y, bb.z, bb.w};
  #pragma unroll
  for (int r = 0; r < 8; ++r) {
    const size_t rowi = (size_t)(row0 + ty * 8 + r);
    float ov[8];
    #pragma unroll
    for (int j = 0; j < 8; ++j) ov[j] = total[r][j] + br8[j];
    float* cp = &C[rowi * N + col0 + tx * 8];
    float4 o0, o1;
    o0.x = ov[0]; o0.y = ov[1]; o0.z = ov[2]; o0.w = ov[3];
    o1.x = ov[4]; o1.y = ov[5]; o1.z = ov[6]; o1.w = ov[7];
    *(float4*)cp = o0;
    *(float4*)(cp + 4) = o1;
    if (ZP) {  // fused bf16x2 truncation split, packed
      uint4 p0, p1;
      p0.x = packsplit(ov[0]); p0.y = packsplit(ov[1]);
      p0.z = packsplit(ov[2]); p0.w = packsplit(ov[3]);
      p1.x = packsplit(ov[4]); p1.y = packsplit(ov[5]);
      p1.z = packsplit(ov[6]); p1.w = packsplit(ov[7]);
      unsigned* zp = &ZP[rowi * N + col0 + tx * 8];
      *(uint4*)zp = p0;
      *(uint4*)(zp + 4) = p1;
    }
  }
}

// ---------------------------------------------------------------------------
// bf16x2 MFMA distance screen (r14 geometry: 32-k stage, 36 KB LDS,
// 128B rows hi 0..63 / lo 64..127, XOR (r&7)<<4). Z pre-split packed u32;
// CB truncation-split inline. Epilogue: shuffle-min then one atomicMin/group.
// ---------------------------------------------------------------------------
__global__ __launch_bounds__(256) void mfma_screen_kernel(
    const unsigned* __restrict__ ZP, const float* __restrict__ CB,
    const float* __restrict__ Z2, const float* __restrict__ C2,
    uint4* __restrict__ recs) {
  __shared__ unsigned short Zs[128 * 64];  // 16 KB
  __shared__ unsigned short Cs[128 * 64];  // 16 KB
  __shared__ int rowminI[128];
  __shared__ int cnt[128];
  __shared__ unsigned short cand[128][12];
  const int tid = threadIdx.x;
  const int wid = tid >> 6, lane = tid & 63;
  const int e0 = blockIdx.x * 128, row0 = blockIdx.y * 128;
  const int wr = (wid >> 1) * 64, wc = (wid & 1) * 64;

  if (tid < 128) { rowminI[tid] = 0x7F800000; cnt[tid] = 0; }

  f32x4 acc[4][4];
  #pragma unroll
  for (int m = 0; m < 4; ++m)
    #pragma unroll
    for (int n = 0; n < 4; ++n)
      #pragma unroll
      for (int j = 0; j < 4; ++j) acc[m][n][j] = 0.f;

  const int stg_r = tid >> 3, stg_kg = (tid & 7) * 4;  // 4 elems per pass

  for (int k0 = 0; k0 < 1024; k0 += 32) {
    __syncthreads();
    #pragma unroll
    for (int s = 0; s < 4; ++s) {
      const int r = stg_r + s * 32;  // 0..127
      const int swz = (r & 7) << 4;
      const int bhi = (r * 128 + stg_kg * 2) ^ swz;
      const int blo = (r * 128 + 64 + stg_kg * 2) ^ swz;
      const uint4 p = *(const uint4*)&ZP[(size_t)(row0 + r) * 1024 + k0 + stg_kg];
      uint2 zh, zl;
      zh.x = (p.x & 0xFFFFu) | (p.y << 16);
      zh.y = (p.z & 0xFFFFu) | (p.w << 16);
      zl.x = (p.x >> 16) | (p.y & 0xFFFF0000u);
      zl.y = (p.z >> 16) | (p.w & 0xFFFF0000u);
      *(uint2*)((char*)Zs + bhi) = zh;
      *(uint2*)((char*)Zs + blo) = zl;
      const float4 cv = *(const float4*)&CB[(size_t)(e0 + r) * 1024 + k0 + stg_kg];
      const float cf[4] = {cv.x, cv.y, cv.z, cv.w};
      unsigned ch[4], cl[4];
      #pragma unroll
      for (int i = 0; i < 4; ++i) {
        const unsigned u = __float_as_uint(cf[i]);
        ch[i] = u & 0xFFFF0000u;
        const float rem = cf[i] - __uint_as_float(ch[i]);
        cl[i] = __float_as_uint(rem) & 0xFFFF0000u;
      }
      uint2 cph, cpl;
      cph.x = (ch[0] >> 16) | ch[1];
      cph.y = (ch[2] >> 16) | ch[3];
      cpl.x = (cl[0] >> 16) | cl[1];
      cpl.y = (cl[2] >> 16) | cl[3];
      *(uint2*)((char*)Cs + bhi) = cph;
      *(uint2*)((char*)Cs + blo) = cpl;
    }
    __syncthreads();
    const int kb2 = 16 * (lane >> 4);
    short8 ah[4], al[4], bh[4], bl[4];
    #pragma unroll
    for (int m = 0; m < 4; ++m) {
      const int r = wr + m * 16 + (lane & 15);
      const int swz = (r & 7) << 4;
      ah[m] = *(const short8*)((const char*)Zs + ((r * 128 + kb2) ^ swz));
      al[m] = *(const short8*)((const char*)Zs + ((r * 128 + 64 + kb2) ^ swz));
    }
    #pragma unroll
    for (int n = 0; n < 4; ++n) {
      const int r = wc + n * 16 + (lane & 15);
      const int swz = (r & 7) << 4;
      bh[n] = *(const short8*)((const char*)Cs + ((r * 128 + kb2) ^ swz));
      bl[n] = *(const short8*)((const char*)Cs + ((r * 128 + 64 + kb2) ^ swz));
    }
    #pragma unroll
    for (int m = 0; m < 4; ++m)
      #pragma unroll
      for (int n = 0; n < 4; ++n) {
        acc[m][n] = __builtin_amdgcn_mfma_f32_16x16x32_bf16(ah[m], bh[n], acc[m][n], 0, 0, 0);
        acc[m][n] = __builtin_amdgcn_mfma_f32_16x16x32_bf16(ah[m], bl[n], acc[m][n], 0, 0, 0);
        acc[m][n] = __builtin_amdgcn_mfma_f32_16x16x32_bf16(al[m], bh[n], acc[m][n], 0, 0, 0);
      }
  }

  // epilogue: d~ values; per-row min via tx-group shuffle then one atomicMin
  float dv[4][4][4];
  #pragma unroll
  for (int m = 0; m < 4; ++m)
    #pragma unroll
    for (int j = 0; j < 4; ++j) {
      const int rg = row0 + wr + m * 16 + (lane >> 4) * 4 + j;
      const float z2r = Z2[rg];
      float lm = FLT_MAX;
      #pragma unroll
      for (int n = 0; n < 4; ++n) {
        const float d = __builtin_fmaf(-2.0f, acc[m][n][j], z2r) +
                        C2[e0 + wc + n * 16 + (lane & 15)];
        dv[m][n][j] = d;
        lm = fminf(lm, d);
      }
      #pragma unroll
      for (int msk = 1; msk < 16; msk <<= 1)
        lm = fminf(lm, __shfl_xor(lm, msk, 64));
      if ((lane & 15) == 0)
        atomicMin(&rowminI[wr + m * 16 + (lane >> 4) * 4 + j], __float_as_int(lm));
    }
  __syncthreads();
  #pragma unroll
  for (int m = 0; m < 4; ++m)
    #pragma unroll
    for (int j = 0; j < 4; ++j) {
      const int rl = wr + m * 16 + (lane >> 4) * 4 + j;
      const float thr = __int_as_float(rowminI[rl]) + SCREEN_DELTA;
      #pragma unroll
      for (int n = 0; n < 4; ++n) {
        if (dv[m][n][j] <= thr) {
          const int pos = atomicAdd(&cnt[rl], 1);
          if (pos < 12)
            cand[rl][pos] = (unsigned short)(e0 + wc + n * 16 + (lane & 15));
        }
      }
    }
  __syncthreads();
  if (tid < 128) {
    uint4 a, b;
    a.x = (unsigned)rowminI[tid];
    a.y = (unsigned)cnt[tid];
    a.z = (unsigned)cand[tid][0] | ((unsigned)cand[tid][1] << 16);
    a.w = (unsigned)cand[tid][2] | ((unsigned)cand[tid][3] << 16);
    b.x = (unsigned)cand[tid][4] | ((unsigned)cand[tid][5] << 16);
    b.y = (unsigned)cand[tid][6] | ((unsigned)cand[tid][7] << 16);
    b.z = (unsigned)cand[tid][8] | ((unsigned)cand[tid][9] << 16);
    b.w = (unsigned)cand[tid][10] | ((unsigned)cand[tid][11] << 16);
    const size_t base = ((size_t)(row0 + tid) * 64 + blockIdx.x) * 2;
    recs[base] = a;
    recs[base + 1] = b;
  }
}

// ---------------------------------------------------------------------------
// Collect + exact rescore + z_q gather + embedding partial. Block per row.
// ---------------------------------------------------------------------------
__global__ __launch_bounds__(256) void collect_rescore_kernel(
    const uint4* __restrict__ recs, const float* __restrict__ Z,
    const float* __restrict__ CB, const float* __restrict__ Z2,
    const float* __restrict__ C2, int* __restrict__ ids,
    float* __restrict__ o_ids, float* __restrict__ o_zq,
    float* __restrict__ esum) {
  __shared__ float zsh[1024];
  __shared__ float gmin_sh;
  __shared__ int lcnt, ovf, ewin;
  __shared__ unsigned short list[64];
  __shared__ unsigned long long kred[4];
  const int row = blockIdx.x, tid = threadIdx.x;
  if (tid == 0) { lcnt = 0; ovf = 0; }
  uint4 r0 = make_uint4(0, 0, 0, 0), r1 = make_uint4(0, 0, 0, 0);
  float mymin = FLT_MAX;
  if (tid < 64) {
    const size_t base = ((size_t)row * 64 + tid) * 2;
    r0 = recs[base];
    r1 = recs[base + 1];
    mymin = __uint_as_float(r0.x);
  }
  for (int i = tid; i < 1024; i += 256) zsh[i] = Z[(size_t)row * 1024 + i];
  if (tid < 64) {
    float m = mymin;
    #pragma unroll
    for (int off = 32; off > 0; off >>= 1) m = fminf(m, __shfl_down(m, off, 64));
    if (tid == 0) gmin_sh = m;
  }
  __syncthreads();
  const float thr = gmin_sh + SCREEN_DELTA;
  if (tid < 64 && mymin <= thr) {
    const int c = (int)r0.y;
    if (c > 12) {
      atomicOr(&ovf, 1);
    } else {
      unsigned short idxs[12];
      idxs[0] = r0.z & 0xFFFF; idxs[1] = r0.z >> 16;
      idxs[2] = r0.w & 0xFFFF; idxs[3] = r0.w >> 16;
      idxs[4] = r1.x & 0xFFFF; idxs[5] = r1.x >> 16;
      idxs[6] = r1.y & 0xFFFF; idxs[7] = r1.y >> 16;
      idxs[8] = r1.z & 0xFFFF; idxs[9] = r1.z >> 16;
      idxs[10] = r1.w & 0xFFFF; idxs[11] = r1.w >> 16;
      for (int i = 0; i < c; ++i) {
        const int pos = atomicAdd(&lcnt, 1);
        if (pos < 64) list[pos] = idxs[i];
        else atomicOr(&ovf, 1);
      }
    }
  }
  __syncthreads();
  const float z2r = Z2[row];
  unsigned long long key = ~0ULL;
  if (ovf) {  // rare: exact full-row scan
    for (int e = tid; e < CBK; e += 256) {
      const float d = chain_d(zsh, &CB[(size_t)e * 1024], z2r, C2[e]);
      const unsigned long long k =
          ((unsigned long long)__float_as_uint(d) << 32) | (unsigned)e;
      key = (k < key) ? k : key;
    }
  } else {
    const int n = lcnt < 64 ? lcnt : 64;
    if (tid < n) {
      const int e = list[tid];
      const float d = chain_d(zsh, &CB[(size_t)e * 1024], z2r, C2[e]);
      key = ((unsigned long long)__float_as_uint(d) << 32) | (unsigned)e;
    }
  }
  #pragma unroll
  for (int off = 32; off > 0; off >>= 1) {
    const unsigned long long o = __shfl_down(key, off, 64);
    key = (o < key) ? o : key;
  }
  if ((tid & 63) == 0) kred[tid >> 6] = key;
  __syncthreads();
  if (tid == 0) {
    unsigned long long k = kred[0];
    k = (kred[1] < k) ? kred[1] : k;
    k = (kred[2] < k) ? kred[2] : k;
    k = (kred[3] < k) ? kred[3] : k;
    const int e = (int)(k & 0xFFFFFFFFu);
    ids[row] = e;
    o_ids[row] = (float)e;
    ewin = e;
  }
  __syncthreads();
  // fused z_q gather + embedding partial (exact z in zsh)
  const int e2 = ewin;
  float s = 0.f;
  for (int i = tid; i < 1024; i += 256) {
    const float c = CB[(size_t)e2 * 1024 + i];
    o_zq[(size_t)row * 1024 + i] = c;
    const float d = zsh[i] - c;
    s = __builtin_fmaf(d, d, s);
  }
  const float r2 = block_reduce_sum(s);
  if (tid == 0) esum[row] = r2;
}

// ---------------------------------------------------------------------------
// bf16 MFMA recon (r11 PASSED, unchanged).
// ---------------------------------------------------------------------------
__global__ __launch_bounds__(256) void mfma_recon_kernel(
    const float* __restrict__ A, const float* __restrict__ B,
    const float* __restrict__ bias, float* __restrict__ C) {
  __shared__ unsigned short Abf[128 * 64];
  __shared__ unsigned short Bbf[128 * 64];
  const int tid = threadIdx.x;
  const int wid = tid >> 6, lane = tid & 63;
  const int row0 = blockIdx.y * 128, col0 = blockIdx.x * 128;
  const int wr = (wid >> 1) * 64, wc = (wid & 1) * 64;

  f32x4 acc[4][4];
  #pragma unroll
  for (int m = 0; m < 4; ++m)
    #pragma unroll
    for (int n = 0; n < 4; ++n)
      #pragma unroll
      for (int j = 0; j < 4; ++j) acc[m][n][j] = 0.f;

  for (int k0 = 0; k0 < 1024; k0 += 64) {
    __syncthreads();
    #pragma unroll
    for (int q = 0; q < 4; ++q) {
      const int g = tid + q * 256;
      const int r = g >> 3;
      const int kg = (g & 7) * 8;
      const float4 a0 = *(const float4*)&A[(size_t)(row0 + r) * 1024 + k0 + kg];
      const float4 a1 = *(const float4*)&A[(size_t)(row0 + r) * 1024 + k0 + kg + 4];
      const float4 b0 = *(const float4*)&B[(size_t)(col0 + r) * 1024 + k0 + kg];
      const float4 b1 = *(const float4*)&B[(size_t)(col0 + r) * 1024 + k0 + kg + 4];
      ushort8 pa, pb;
      pa[0] = f2bf(a0.x); pa[1] = f2bf(a0.y); pa[2] = f2bf(a0.z); pa[3] = f2bf(a0.w);
      pa[4] = f2bf(a1.x); pa[5] = f2bf(a1.y); pa[6] = f2bf(a1.z); pa[7] = f2bf(a1.w);
      pb[0] = f2bf(b0.x); pb[1] = f2bf(b0.y); pb[2] = f2bf(b0.z); pb[3] = f2bf(b0.w);
      pb[4] = f2bf(b1.x); pb[5] = f2bf(b1.y); pb[6] = f2bf(b1.z); pb[7] = f2bf(b1.w);
      const int byte = (r * 128 + kg * 2) ^ ((r & 7) << 4);
      *(ushort8*)((char*)Abf + byte) = pa;
      *(ushort8*)((char*)Bbf + byte) = pb;
    }
    __syncthreads();
    #pragma unroll
    for (int kh = 0; kh < 2; ++kh) {
      const int kb = kh * 32 + 8 * (lane >> 4);
      short8 afr[4], bfr[4];
      #pragma unroll
      for (int m = 0; m < 4; ++m) {
        const int r = wr + m * 16 + (lane & 15);
        const int byte = (r * 128 + kb * 2) ^ ((r & 7) << 4);
        afr[m] = *(const short8*)((const char*)Abf + byte);
      }
      #pragma unroll
      for (int n = 0; n < 4; ++n) {
        const int r = wc + n * 16 + (lane & 15);
        const int byte = (r * 128 + kb * 2) ^ ((r & 7) << 4);
        bfr[n] = *(const short8*)((const char*)Bbf + byte);
      }
      #pragma unroll
      for (int m = 0; m < 4; ++m)
        #pragma unroll
        for (int n = 0; n < 4; ++n)
          acc[m][n] = __builtin_amdgcn_mfma_f32_16x16x32_bf16(
              afr[m], bfr[n], acc[m][n], 0, 0, 0);
    }
  }

  #pragma unroll
  for (int m = 0; m < 4; ++m)
    #pragma unroll
    for (int n = 0; n < 4; ++n) {
      const int col = col0 + wc + n * 16 + (lane & 15);
      const float bc = bias[col];
      #pragma unroll
      for (int j = 0; j < 4; ++j) {
        const int row = row0 + wr + m * 16 + (lane >> 4) * 4 + j;
        C[(size_t)row * 2048 + col] = acc[m][n][j] + bc;
      }
    }
}

// ---------------------------------------------------------------------------
// numpy pairwise_sum emulation of sum(x*x) over rows of 1024 (unchanged).
// ---------------------------------------------------------------------------
__global__ __launch_bounds__(256) void sumsq1024_kernel(
    const float* __restrict__ X, float* __restrict__ out) {
  __shared__ float rows[4][1024];
  __shared__ float leaves[4][8];
  const int tid = threadIdx.x;
  const int row0 = blockIdx.x * 4;
  for (int i = tid; i < 4096; i += 256)
    rows[i >> 10][i & 1023] = X[(size_t)row0 * 1024 + i];
  __syncthreads();
  if (tid < 32) {
    const int r = tid >> 3, lf = tid & 7;
    const float* a = &rows[r][lf * 128];
    float s0 = sqf(a[0]), s1 = sqf(a[1]), s2 = sqf(a[2]), s3 = sqf(a[3]);
    float s4 = sqf(a[4]), s5 = sqf(a[5]), s6 = sqf(a[6]), s7 = sqf(a[7]);
    for (int i = 8; i < 128; i += 8) {
      s0 = s0 + sqf(a[i + 0]); s1 = s1 + sqf(a[i + 1]);
      s2 = s2 + sqf(a[i + 2]); s3 = s3 + sqf(a[i + 3]);
      s4 = s4 + sqf(a[i + 4]); s5 = s5 + sqf(a[i + 5]);
      s6 = s6 + sqf(a[i + 6]); s7 = s7 + sqf(a[i + 7]);
    }
    leaves[r][lf] = ((s0 + s1) + (s2 + s3)) + ((s4 + s5) + (s6 + s7));
  }
  __syncthreads();
  if (tid < 4) {
    const float* L = leaves[tid];
    const float p01 = L[0] + L[1], p23 = L[2] + L[3];
    const float p45 = L[4] + L[5], p67 = L[6] + L[7];
    out[row0 + tid] = ((p01 + p23) + (p45 + p67));
  }
}

__global__ __launch_bounds__(256) void rowdot_bias_kernel(
    const float* __restrict__ W, const float* __restrict__ v,
    const float* __restrict__ b2, float* __restrict__ out) {
  const int row = blockIdx.x;
  const float4 w4 = *(const float4*)&W[(size_t)row * 1024 + threadIdx.x * 4];
  const float4 v4 = *(const float4*)&v[threadIdx.x * 4];
  const float s = w4.x * v4.x + w4.y * v4.y + w4.z * v4.z + w4.w * v4.w;
  const float r = block_reduce_sum(s);
  if (threadIdx.x == 0) out[row] = r + b2[row];
}

__global__ __launch_bounds__(256) void sqdiff_partial_kernel(
    const float* __restrict__ a, const float* __restrict__ b,
    float* __restrict__ part) {
  const size_t base = (size_t)blockIdx.x * 2048 + (size_t)threadIdx.x * 8;
  const float4 x0 = *(const float4*)&a[base];
  const float4 x1 = *(const float4*)&a[base + 4];
  const float4 y0 = *(const float4*)&b[base];
  const float4 y1 = *(const float4*)&b[base + 4];
  float s = 0.f;
  float d;
  d = x0.x - y0.x; s += d * d; d = x0.y - y0.y; s += d * d;
  d = x0.z - y0.z; s += d * d; d = x0.w - y0.w; s += d * d;
  d = x1.x - y1.x; s += d * d; d = x1.y - y1.y; s += d * d;
  d = x1.z - y1.z; s += d * d; d = x1.w - y1.w; s += d * d;
  const float r = block_reduce_sum(s);
  if (threadIdx.x == 0) part[blockIdx.x] = r;
}

__global__ __launch_bounds__(256) void final_losses_kernel(
    const float* __restrict__ rp, const float* __restrict__ esum,
    float* __restrict__ o) {
  __shared__ double sh[4];
  const int lane = threadIdx.x & 63, w = threadIdx.x >> 6;
  double s = 0.0;
  for (int i = threadIdx.x; i < 8192; i += 256) s += (double)rp[i];
  #pragma unroll
  for (int off = 32; off > 0; off >>= 1) s += __shfl_down(s, off, 64);
  if (lane == 0) sh[w] = s;
  __syncthreads();
  double rl = 0.0;
  if (threadIdx.x == 0) rl = (sh[0] + sh[1] + sh[2] + sh[3]) / ((double)N_ROWS * IN_DIM);
  __syncthreads();
  double s2 = 0.0;
  for (int i = threadIdx.x; i < 8192; i += 256) s2 += (double)esum[i];
  #pragma unroll
  for (int off = 32; off > 0; off >>= 1) s2 += __shfl_down(s2, off, 64);
  if (lane == 0) sh[w] = s2;
  __syncthreads();
  if (threadIdx.x == 0) {
    const double el = (sh[0] + sh[1] + sh[2] + sh[3]) / ((double)N_ROWS * DIM);
    o[0] = (float)(rl + el + 0.25 * el);
    o[1] = (float)rl;
    o[2] = (float)el;
    o[3] = (float)el;
  }
}

extern "C" void kernel_launch(void* const* d_in, const int* in_sizes, int n_in,
                              void* d_out, int out_size, void* d_ws, size_t ws_size,
                              hipStream_t stream) {
  const float* roi   = (const float*)d_in[0];
  const float* W_in  = (const float*)d_in[1];
  const float* b_in  = (const float*)d_in[2];
  const float* W_enc = (const float*)d_in[3];
  const float* b_enc = (const float*)d_in[4];
  const float* cb    = (const float*)d_in[5];
  const float* W_dec = (const float*)d_in[6];
  const float* b_dec = (const float*)d_in[7];
  const float* W_out = (const float*)d_in[8];
  const float* b_out = (const float*)d_in[9];

  float* out = (float*)d_out;
  float* o_ids   = out;
  float* o_zq    = out + 8192;
  float* o_recon = out + 8192 + (size_t)N_ROWS * DIM;
  float* o_scal  = out + 8192 + (size_t)N_ROWS * DIM + (size_t)N_ROWS * IN_DIM;

  // ws layout (float offsets)
  float*  ws    = (float*)d_ws;
  float*  W_dc  = ws;                          // 2,097,152
  float*  z2    = ws + 2097152;                // 8192
  float*  c2    = ws + 2105344;                // 8192
  int*    ids   = (int*)(ws + 2113536);        // 8192
  float*  b_dc  = ws + 2121728;                // 2048
  float*  esum  = ws + 2123776;                // 8192 (per-row embedding sums)
  float*  rp    = ws + 2131968;                // 8192

  // Scratch reuse:
  //  o_recon (64 MB): t (f32, 1st half) dead after z-GEMM -> recs (16 MB)
  //    live there during screen/collect. z (f32) in 2nd half, live until
  //    collect. recon overwrites everything at the end.
  //  o_zq region (32 MB): zpack (u32 8192x1024, exact fit) written by the
  //    z-GEMM epilogue, consumed by screen; collect then overwrites with z_q.
  float*    t     = o_recon;
  float*    z     = o_recon + (size_t)N_ROWS * DIM;
  uint4*    recs  = (uint4*)o_recon;           // over dead t
  unsigned* zpack = (unsigned*)o_zq;

  // decoder fusion (2%-threshold outputs)
  rowdot_bias_kernel<<<IN_DIM, 256, 0, stream>>>(W_out, b_dec, b_out, b_dc);
  gemm128<false><<<dim3(DIM / 128, IN_DIM / 128), 256, 0, stream>>>(
      W_out, W_dec, nullptr, W_dc, IN_DIM, DIM, DIM);

  // ---- np-f32 emulated encoder (bit-exact chains) ----
  emul_gemm_kernel<<<dim3(DIM / 128, N_ROWS / 128), 256, 0, stream>>>(
      roi, W_in, b_in, t, nullptr, DIM, IN_DIM, IN_DIM, IN_DIM,
      PANEL_MASK_K2048_C32);
  emul_gemm_kernel<<<dim3(DIM / 128, N_ROWS / 128), 256, 0, stream>>>(
      t, W_enc, b_enc, z, zpack, DIM, DIM, DIM, DIM, PANEL_MASK_K1024_C32);

  // ---- np pairwise row sums of squares ----
  sumsq1024_kernel<<<N_ROWS / 4, 256, 0, stream>>>(z, z2);
  sumsq1024_kernel<<<CBK / 4, 256, 0, stream>>>(cb, c2);

  // ---- certified MFMA screen (recs over dead t region) ----
  mfma_screen_kernel<<<dim3(CBK / 128, N_ROWS / 128), 256, 0, stream>>>(
      zpack, cb, z2, c2, recs);
  // ---- exact rescore + z_q gather + embedding partials ----
  collect_rescore_kernel<<<N_ROWS, 256, 0, stream>>>(
      recs, z, cb, z2, c2, ids, o_ids, o_zq, esum);

  // recon via bf16 MFMA (overwrites recs/z region AFTER collect consumed them)
  mfma_recon_kernel<<<dim3(IN_DIM / 128, N_ROWS / 128), 256, 0, stream>>>(
      o_zq, W_dc, b_dc, o_recon);

  sqdiff_partial_kernel<<<(N_ROWS * IN_DIM) / 2048, 256, 0, stream>>>(
      o_recon, roi, rp);
  final_losses_kernel<<<1, 256, 0, stream>>>(rp, esum, o_scal);
}